// Round 17
// baseline (125.106 us; speedup 1.0000x reference)
//
#include <hip/hip_runtime.h>
#include <hip/hip_bf16.h>
#include <math.h>

#define N_PTS 32768
#define IN_F  256
#define NUM_CAT 16
#define CF    4096
#define NSEG  6
#define OUTK  50
#define BN_EPS 1e-5f

typedef unsigned short u16;
typedef __attribute__((ext_vector_type(8))) short bf16x8;
typedef __attribute__((ext_vector_type(4))) float f32x4;
typedef __attribute__((ext_vector_type(4))) unsigned int u32x4;
typedef __attribute__((ext_vector_type(8))) unsigned short u16x8;

// ---- ws layout (float offsets) ----
#define OFF_G     0u          // 256*256
#define OFF_FBAR  65536u      // 256
#define OFF_LUT   65792u      // TILECAT LUT: 528 ints (reuses old SCALE region)
#define OFF_INT   73984u      // int region (33440 ints)
#define OFF_FB    107424u     // F bf16 [32768][256]
#define OFF_FBT   4301728u    // F^T bf16 [256][32768]
#define OFF_W1T   8496032u    // W1T bf16 [16][256 n][256 k]
#define OFF_GP    9020320u    // Gram partials [chunk][49152] (3 tiles x 128x128)
#define OFF_VP    OFF_GP              // 8 * 4096 floats (after kC)
#define OFF_MU    (OFF_GP + 32768u)   // 4096 floats
#define IO_CATOFF 16          // 17 ints
#define IO_ORDER  67          // 32768 ints
#define IO_PC     32835       // u16[64][16]

__device__ __forceinline__ void gload_lds16(const void* g, void* l) {
    __builtin_amdgcn_global_load_lds(
        (const __attribute__((address_space(1))) void*)g,
        (__attribute__((address_space(3))) void*)l,
        16, 0, 0);
}
__device__ __forceinline__ u16 f2bf(float f) {
    unsigned int u = __float_as_uint(f);
    return (u16)((u + 0x7FFF + ((u >> 16) & 1)) >> 16);
}
__device__ __forceinline__ float bf2f(u16 h) {
    return __uint_as_float((unsigned int)h << 16);
}

// ============ kA: F->Fb/FbT convert (2048) | W1->W1T (256) | hist partials (64) ====
__global__ __launch_bounds__(256) void kA(const float* __restrict__ F,
                                          const float* __restrict__ W1,
                                          const int* __restrict__ cats,
                                          u16* __restrict__ Fb,
                                          u16* __restrict__ FbT,
                                          u16* __restrict__ W1T,
                                          float* __restrict__ ws) {
    const int b = blockIdx.x;
    const int tid = threadIdx.x;
    __shared__ u16 T[64][72];
    __shared__ int h[16];

    if (b < 2048) {
        const int pb = b >> 2, fb = b & 3;
        const int p0 = pb * 64, f0 = fb * 64;
        {
            int p = tid >> 2, fq = tid & 3;
            const float* src = &F[(size_t)(p0 + p) * IN_F + f0 + fq * 16];
            u16x8 o0, o1;
            float4 v0 = *(const float4*)&src[0];
            float4 v1 = *(const float4*)&src[4];
            float4 v2 = *(const float4*)&src[8];
            float4 v3 = *(const float4*)&src[12];
            o0[0]=f2bf(v0.x); o0[1]=f2bf(v0.y); o0[2]=f2bf(v0.z); o0[3]=f2bf(v0.w);
            o0[4]=f2bf(v1.x); o0[5]=f2bf(v1.y); o0[6]=f2bf(v1.z); o0[7]=f2bf(v1.w);
            o1[0]=f2bf(v2.x); o1[1]=f2bf(v2.y); o1[2]=f2bf(v2.z); o1[3]=f2bf(v2.w);
            o1[4]=f2bf(v3.x); o1[5]=f2bf(v3.y); o1[6]=f2bf(v3.z); o1[7]=f2bf(v3.w);
            u16* dst = &Fb[(size_t)(p0 + p) * IN_F + f0 + fq * 16];
            *(u16x8*)dst = o0; *(u16x8*)&dst[8] = o1;
            *(u16x8*)&T[p][fq * 16] = o0; *(u16x8*)&T[p][fq * 16 + 8] = o1;
        }
        __syncthreads();
        {
            int f = tid >> 2, pq = tid & 3;
            u16x8 a0, a1;
#pragma unroll
            for (int m = 0; m < 8; m++) { a0[m] = T[pq*16 + m][f]; a1[m] = T[pq*16 + 8 + m][f]; }
            u16* dst = &FbT[(size_t)(f0 + f) * N_PTS + p0 + pq * 16];
            *(u16x8*)dst = a0; *(u16x8*)&dst[8] = a1;
        }
    } else if (b < 2304) {
        const int bb = b - 2048;
        const int kb = bb & 3, jb = bb >> 2;
        {
            int kk = tid >> 2, j4 = (tid & 3) * 16;
            const float* src = &W1[(size_t)(kb * 64 + kk) * CF + jb * 64 + j4];
#pragma unroll
            for (int q = 0; q < 4; q++) {
                float4 v = *(const float4*)&src[q * 4];
                T[kk][j4 + q * 4 + 0] = f2bf(v.x); T[kk][j4 + q * 4 + 1] = f2bf(v.y);
                T[kk][j4 + q * 4 + 2] = f2bf(v.z); T[kk][j4 + q * 4 + 3] = f2bf(v.w);
            }
        }
        __syncthreads();
        {
            int jj = tid >> 2, ks = (tid & 3) * 16;
            int c = jb >> 2, n = (jb & 3) * 64 + jj;
            u16* dst = &W1T[((size_t)(c * 256 + n)) * 256 + kb * 64 + ks];
            u16x8 o0, o1;
#pragma unroll
            for (int m = 0; m < 8; m++) { o0[m] = T[ks + m][jj]; o1[m] = T[ks + 8 + m][jj]; }
            *(u16x8*)dst = o0;
            *(u16x8*)&dst[8] = o1;
        }
    } else {
        const int hb = b - 2304;
        if (tid < 16) h[tid] = 0;
        __syncthreads();
        const int n0 = hb * 512;
        atomicAdd(&h[cats[n0 + tid]], 1);
        atomicAdd(&h[cats[n0 + 256 + tid]], 1);
        __syncthreads();
        if (tid < 16) {
            u16* pc = (u16*)((int*)(ws + OFF_INT) + IO_PC);
            pc[hb * 16 + tid] = (u16)h[tid];
        }
    }
}

// ============ kB: Gram 128x128 tiles (3*nchunk) | column means (256) ============
__global__ __launch_bounds__(512) void kB(const u16* __restrict__ FbT,
                                          float* __restrict__ ws,
                                          int nchunk, int Kc) {
    const int tid = threadIdx.x;
    __shared__ __align__(16) u16 SA[2][8192];
    __shared__ __align__(16) u16 SB[2][8192];
    __shared__ float ps[8];

    if ((int)blockIdx.x < 3 * nchunk) {
        const int tile = blockIdx.x % 3, chunk = blockIdx.x / 3;
        const int i0 = (tile == 2) ? 128 : 0;
        const int j0 = (tile == 0) ? 0 : 128;
        const bool diag = (tile != 1);
        const int r0 = chunk * Kc;
        const int wv = tid >> 6, ln = tid & 63, g = ln >> 4, r16 = ln & 15;

        const int f0_ = (wv * 2 + 0) * 64 + ln, f1_ = (wv * 2 + 1) * 64 + ln;
        const int row0 = f0_ >> 3, u0 = f0_ & 7, k0off = ((u0 ^ (row0 & 7)) << 3);
        const int row1 = f1_ >> 3, u1 = f1_ & 7, k1off = ((u1 ^ (row1 & 7)) << 3);

        f32x4 acc8[8];
#pragma unroll
        for (int nt = 0; nt < 8; nt++)
#pragma unroll
            for (int i = 0; i < 4; i++) acc8[nt][i] = 0.f;

        const int nslab = Kc >> 6;
#define KB_STAGE(s, bf)                                                            \
        {   int p0s = r0 + (s) * 64;                                               \
            gload_lds16(FbT + (size_t)(i0 + row0) * N_PTS + p0s + k0off,           \
                        (char*)SA[bf] + (wv * 2 + 0) * 1024);                      \
            gload_lds16(FbT + (size_t)(i0 + row1) * N_PTS + p0s + k1off,           \
                        (char*)SA[bf] + (wv * 2 + 1) * 1024);                      \
            if (!diag) {                                                           \
                gload_lds16(FbT + (size_t)(j0 + row0) * N_PTS + p0s + k0off,       \
                            (char*)SB[bf] + (wv * 2 + 0) * 1024);                  \
                gload_lds16(FbT + (size_t)(j0 + row1) * N_PTS + p0s + k1off,       \
                            (char*)SB[bf] + (wv * 2 + 1) * 1024);                  \
            }                                                                      \
        }

        KB_STAGE(0, 0);
        __syncthreads();
        for (int s = 0; s < nslab; s++) {
            const int bf = s & 1;
            if (s + 1 < nslab) KB_STAGE(s + 1, bf ^ 1);
            const char* BB = diag ? (const char*)SA[bf] : (const char*)SB[bf];
#pragma unroll
            for (int ks = 0; ks < 2; ks++) {
                const int row = wv * 16 + r16;
                const int pha = ((ks * 4 + g) ^ (row & 7)) * 16;
                bf16x8 a = *(const bf16x8*)((const char*)SA[bf] + row * 128 + pha);
#pragma unroll
                for (int nt = 0; nt < 8; nt++) {
                    const int cr = nt * 16 + r16;
                    const int phb = ((ks * 4 + g) ^ (cr & 7)) * 16;
                    bf16x8 bb = *(const bf16x8*)(BB + cr * 128 + phb);
                    acc8[nt] = __builtin_amdgcn_mfma_f32_16x16x32_bf16(a, bb, acc8[nt], 0, 0, 0);
                }
            }
            __syncthreads();
        }
        float* Gp = ws + OFF_GP + (size_t)chunk * 49152 + tile * 16384;
#pragma unroll
        for (int nt = 0; nt < 8; nt++)
#pragma unroll
            for (int i = 0; i < 4; i++)
                Gp[(wv * 16 + g * 4 + i) * 128 + nt * 16 + r16] = acc8[nt][i];
    } else {
        const int row = blockIdx.x - 3 * nchunk;
        const u16* r = FbT + (size_t)row * N_PTS;
        float s = 0.f;
        for (int i = tid * 8; i < N_PTS; i += 4096) {
            u16x8 v = *(const u16x8*)&r[i];
#pragma unroll
            for (int m = 0; m < 8; m++) s += bf2f(v[m]);
        }
#pragma unroll
        for (int off = 32; off >= 1; off >>= 1) s += __shfl_xor(s, off);
        if ((tid & 63) == 0) ps[tid >> 6] = s;
        __syncthreads();
        if (tid == 0) {
            float t = 0.f;
#pragma unroll
            for (int w = 0; w < 8; w++) t += ps[w];
            ws[OFF_FBAR + row] = t * (1.0f / N_PTS);
        }
    }
}

// ============ kC: reduce Gram partials -> G (192) | scatter + TILECAT LUT (64) ====
__global__ __launch_bounds__(256) void kC(const int* __restrict__ cats,
                                          float* __restrict__ ws, int nchunk) {
    const int tid = threadIdx.x;
    int* wi = (int*)(ws + OFF_INT);
    __shared__ int tot[16], bbs[16], coff[17], lh[16], tst[17];

    if (blockIdx.x < 192) {
        const int e = blockIdx.x * 256 + tid;
        const float* p = ws + OFF_GP + e;
        float s = 0.f;
        for (int c = 0; c < nchunk; c++) s += p[(size_t)c * 49152];
        const int t = e >> 14, x = (e >> 7) & 127, y = e & 127;
        const int a = ((t == 2) ? 128 : 0) + x;
        const int bcol = ((t == 0) ? 0 : 128) + y;
        ws[OFF_G + a * 256 + bcol] = s;
        ws[OFF_G + bcol * 256 + a] = s;
    } else {
        const int sb = blockIdx.x - 192;
        const u16* pc = (const u16*)(wi + IO_PC);
        if (tid < 16) {
            int T = 0, B = 0;
            for (int b2 = 0; b2 < 64; b2++) {
                int v = pc[b2 * 16 + tid];
                T += v;
                if (b2 < sb) B += v;
            }
            tot[tid] = T; bbs[tid] = B; lh[tid] = 0;
        }
        __syncthreads();
        if (tid == 0) {
            int co = 0, ts = 0;
            for (int c = 0; c < 16; c++) {
                coff[c] = co; tst[c] = ts;
                co += tot[c]; ts += (tot[c] + 63) >> 6;
            }
            coff[16] = co; tst[16] = ts;
        }
        __syncthreads();
        const int n0 = sb * 512;
        {
            int cA = cats[n0 + tid];
            int rA = atomicAdd(&lh[cA], 1);
            wi[IO_ORDER + coff[cA] + bbs[cA] + rA] = n0 + tid;
        }
        {
            int cB = cats[n0 + 256 + tid];
            int rB = atomicAdd(&lh[cB], 1);
            wi[IO_ORDER + coff[cB] + bbs[cB] + rB] = n0 + 256 + tid;
        }
        if (sb == 0) {
            if (tid < 17) wi[IO_CATOFF + tid] = coff[tid];
            int* lut = (int*)(ws + OFF_LUT);
            // parallel LUT fill: each thread handles tiles tid, tid+256
            for (int t = tid; t < 528; t += 256) {
                int info = -1;
                if (t < tst[16]) {
                    int c = 0;
                    while (!(t >= tst[c] && t < tst[c + 1])) c++;
                    int lt = t - tst[c];
                    int npts = min(64, tot[c] - lt * 64);
                    int b = coff[c] + lt * 64;
                    info = c | ((npts - 1) << 4) | (b << 10);
                }
                lut[t] = info;
            }
        }
    }
}

// ============ kD: w^T G w split-b partials (128 colgrp x 8 b-splits) ============
__global__ __launch_bounds__(256) void kD(const float* __restrict__ W1,
                                          const u16* __restrict__ W1T,
                                          float* __restrict__ ws) {
    const int tid = threadIdx.x;
    const int jg = blockIdx.x >> 3, sp = blockIdx.x & 7;
    const int j0 = jg * 32;
    const int c = jg >> 3, n0 = (jg & 7) * 32;
    __shared__ float pwv[32][4], pwm[32][4];

    float acc[32];
#pragma unroll
    for (int jj = 0; jj < 32; jj++) acc[jj] = 0.f;

    const float* Gs = ws + OFF_G + (size_t)(sp * 32) * 256;
#pragma unroll 2
    for (int b = 0; b < 32; b++) {
        const float g = Gs[b * 256 + tid];
        const float* wrow = W1 + (size_t)(sp * 32 + b) * CF + j0;
#pragma unroll
        for (int jj = 0; jj < 32; jj++)
            acc[jj] += g * wrow[jj];
    }

    const int lane = tid & 63, wave = tid >> 6;
    const float fb = ws[OFF_FBAR + tid];
#pragma unroll
    for (int jj = 0; jj < 32; jj++) {
        const float wk = bf2f(W1T[((size_t)(c * 256 + n0 + jj)) * 256 + tid]);
        float v = wk * acc[jj];
#pragma unroll
        for (int off = 32; off >= 1; off >>= 1) v += __shfl_xor(v, off);
        if (lane == 0) pwv[jj][wave] = v;
        if (sp == 0) {
            float m = fb * wk;
#pragma unroll
            for (int off = 32; off >= 1; off >>= 1) m += __shfl_xor(m, off);
            if (lane == 0) pwm[jj][wave] = m;
        }
    }
    __syncthreads();
    if (tid < 32) {
        float v = pwv[tid][0] + pwv[tid][1] + pwv[tid][2] + pwv[tid][3];
        ws[OFF_VP + sp * 4096 + j0 + tid] = v;
        if (sp == 0) {
            float m = pwm[tid][0] + pwm[tid][1] + pwm[tid][2] + pwm[tid][3];
            ws[OFF_MU + j0 + tid] = m;
        }
    }
}

// ============ K5: bf16-MFMA GEMM — pinned W + MFMA epilogue + LUT dispatch ============
__global__ __launch_bounds__(512, 4) void k5_mfma(const u16* __restrict__ Fb,
                                                  const u16* __restrict__ W1T,
                                                  const float* __restrict__ Wc,
                                                  const float* __restrict__ gamma,
                                                  const float* __restrict__ beta,
                                                  const float* __restrict__ bias,
                                                  const int* __restrict__ shifts,
                                                  const int* __restrict__ seg_lens,
                                                  const float* __restrict__ ws,
                                                  float* __restrict__ out) {
    const int* wi = (const int*)(ws + OFF_INT);
    const int bid = blockIdx.x;
    const int t = (bid & 7) * 66 + (bid >> 3);   // 528 = 8 x 66, bijective
    const int info = ((const int*)(ws + OFF_LUT))[t];
    if (info < 0) return;
    const int c    = info & 15;
    const int npts = ((info >> 4) & 63) + 1;
    const int base = ((unsigned)info) >> 10;
    const int tid = threadIdx.x;
    const int wv = tid >> 6, ln = tid & 63;
    const int g = ln >> 4, r16 = ln & 15, r7 = r16 & 7;

    __shared__ __align__(16) u16 Fl[16384];     // 32 KB: F tile, then X
    __shared__ float red[64][8][8];             // 16 KB
    __shared__ int plds[64];

    if (tid < 64) plds[tid] = wi[IO_ORDER + base + min(tid, npts - 1)];
    const int col0 = wv * 32 + r16, col1 = col0 + 16;
    const float biasj = ((tid & 7) < 6) ? bias[tid & 7] : 0.f;
    const int shc = shifts[c], lnc = seg_lens[c];

    // Wc B-fragment: lane holds B[k = wv*32 + g*8 + j][n = r16], n>=6 -> 0
    bf16x8 bwc;
#pragma unroll
    for (int j = 0; j < 8; j++) {
        float v = (r16 < 6) ? Wc[(size_t)c * 1536 + (wv * 32 + g * 8 + j) * 6 + r16] : 0.f;
        bwc[j] = (short)f2bf(v);
    }
    __syncthreads();                            // plds visible

    // ---- issue F staging (gathered, swizzled source) ----
#pragma unroll
    for (int s = 0; s < 4; s++) {
        int flat = (wv * 4 + s) * 64 + ln;
        int pt = flat >> 5, u = flat & 31;
        const u16* src = Fb + (size_t)plds[pt] * 256 + ((u ^ (pt & 7)) << 3);
        gload_lds16(src, (char*)Fl + (size_t)(wv * 4 + s) * 1024);
    }

    // ---- asm-pinned W loads: 16 x 16B into 64 VGPRs ----
    const u16* W1Tc = W1T + (size_t)c * 65536;
    unsigned long long a0 = (unsigned long long)(W1Tc + (size_t)col0 * 256 + g * 8);
    unsigned long long a1 = (unsigned long long)(W1Tc + (size_t)col1 * 256 + g * 8);
    u32x4 wr[16];
#pragma unroll
    for (int kc = 0; kc < 8; kc++) {
        asm volatile("global_load_dwordx4 %0, %1, off offset:%2"
                     : "=v"(wr[kc * 2])     : "v"(a0), "i"(kc * 64));
        asm volatile("global_load_dwordx4 %0, %1, off offset:%2"
                     : "=v"(wr[kc * 2 + 1]) : "v"(a1), "i"(kc * 64));
    }

    __syncthreads();    // implicit s_waitcnt vmcnt(0): F staged AND all wr ready

    f32x4 acc[4][2];
#pragma unroll
    for (int mt = 0; mt < 4; mt++)
#pragma unroll
        for (int nt = 0; nt < 2; nt++)
#pragma unroll
            for (int i = 0; i < 4; i++) acc[mt][nt][i] = 0.f;

#pragma unroll
    for (int kc = 0; kc < 8; kc++) {
        bf16x8 b0 = __builtin_bit_cast(bf16x8, wr[kc * 2]);
        bf16x8 b1 = __builtin_bit_cast(bf16x8, wr[kc * 2 + 1]);
#pragma unroll
        for (int mt = 0; mt < 4; mt++) {
            int row = mt * 16 + r16;
            int ph = ((kc * 4 + g) ^ r7) * 16;
            bf16x8 af = *(const bf16x8*)((const char*)Fl + (size_t)row * 512 + ph);
            acc[mt][0] = __builtin_amdgcn_mfma_f32_16x16x32_bf16(af, b0, acc[mt][0], 0, 0, 0);
            acc[mt][1] = __builtin_amdgcn_mfma_f32_16x16x32_bf16(af, b1, acc[mt][1], 0, 0, 0);
        }
    }

    // ---- BN constants inline from VP/MU ----
    float vv0 = 0.f, vv1 = 0.f;
#pragma unroll
    for (int sp = 0; sp < 8; sp++) {
        vv0 += ws[OFF_VP + sp * 4096 + c * 256 + col0];
        vv1 += ws[OFF_VP + sp * 4096 + c * 256 + col1];
    }
    const float mu0 = ws[OFF_MU + c * 256 + col0];
    const float mu1 = ws[OFF_MU + c * 256 + col1];
    const float sc0 = gamma[c * 256 + col0] * rsqrtf(vv0 * (1.0f / N_PTS) - mu0 * mu0 + BN_EPS);
    const float sc1 = gamma[c * 256 + col1] * rsqrtf(vv1 * (1.0f / N_PTS) - mu1 * mu1 + BN_EPS);
    const float sh0 = beta[c * 256 + col0] - mu0 * sc0;
    const float sh1 = beta[c * 256 + col1] - mu1 * sc1;

    __syncthreads();    // all Fl reads done; safe to overwrite with X

    // ---- BN + LeakyReLU -> X bf16 into Fl (swizzled 16B units by row&7) ----
#pragma unroll
    for (int mt = 0; mt < 4; mt++)
#pragma unroll
        for (int i = 0; i < 4; i++) {
            const int row = mt * 16 + g * 4 + i;
            float x0 = acc[mt][0][i] * sc0 + sh0;  x0 = (x0 >= 0.f) ? x0 : 0.2f * x0;
            float x1 = acc[mt][1][i] * sc1 + sh1;  x1 = (x1 >= 0.f) ? x1 : 0.2f * x1;
            {
                const int u = (col0 >> 3) ^ (row & 7);
                *(u16*)((char*)Fl + row * 512 + u * 16 + (col0 & 7) * 2) = f2bf(x0);
            }
            {
                const int u = (col1 >> 3) ^ (row & 7);
                *(u16*)((char*)Fl + row * 512 + u * 16 + (col1 & 7) * 2) = f2bf(x1);
            }
        }
    __syncthreads();

    // ---- logits partials via MFMA: X (wave K-slice) x Wc ----
    f32x4 zero = {0.f, 0.f, 0.f, 0.f};
#pragma unroll
    for (int mt = 0; mt < 4; mt++) {
        const int ar = mt * 16 + r16;
        const int au = (wv * 4 + g) ^ (ar & 7);
        bf16x8 ax = *(const bf16x8*)((const char*)Fl + ar * 512 + au * 16);
        f32x4 pc = __builtin_amdgcn_mfma_f32_16x16x32_bf16(ax, bwc, zero, 0, 0, 0);
        if (r16 < 8) {
#pragma unroll
            for (int i = 0; i < 4; i++)
                red[mt * 16 + g * 4 + i][wv][r16] = pc[i];
        }
    }
    __syncthreads();

    // ---- finalize: 64 pts x 8 lanes ----
    {
        const int lpt = tid >> 3, j = tid & 7;
        float v = -1e30f;
        if (j < 6) {
            v = biasj;
#pragma unroll
            for (int w = 0; w < 8; w++) v += red[lpt][w][j];
        }
        float mx = v;
        mx = fmaxf(mx, __shfl_xor(mx, 1));
        mx = fmaxf(mx, __shfl_xor(mx, 2));
        mx = fmaxf(mx, __shfl_xor(mx, 4));
        float e = (j < 6) ? expf(v - mx) : 0.f;
        float se = e;
        se += __shfl_xor(se, 1);
        se += __shfl_xor(se, 2);
        se += __shfl_xor(se, 4);
        float lsm = v - (mx + logf(se));
        if (lpt < npts) {
            const int pid = plds[lpt];
            float* orow = out + (size_t)pid * OUTK;
            const int gb = ln & 56;
#pragma unroll
            for (int it = 0; it < 7; it++) {
                int k = j + it * 8;
                int jj = k - shc;
                int jc = min(max(jj, 0), 5);
                float val = __shfl(lsm, gb | jc);
                if (k < OUTK)
                    orow[k] = (jj >= 0 && jj < lnc) ? val : 0.f;
            }
        }
    }
}

extern "C" void kernel_launch(void* const* d_in, const int* in_sizes, int n_in,
                              void* d_out, int out_size, void* d_ws, size_t ws_size,
                              hipStream_t stream) {
    const float* F      = (const float*)d_in[0];
    const float* W1     = (const float*)d_in[1];
    const float* gamma  = (const float*)d_in[2];
    const float* beta   = (const float*)d_in[3];
    const float* Wc     = (const float*)d_in[4];
    const float* bias   = (const float*)d_in[5];
    const int*  cats    = (const int*)d_in[6];
    const int*  shifts  = (const int*)d_in[7];
    const int*  seglens = (const int*)d_in[8];
    float* out = (float*)d_out;
    float* ws  = (float*)d_ws;
    u16* Fb  = (u16*)(ws + OFF_FB);
    u16* FbT = (u16*)(ws + OFF_FBT);
    u16* W1T = (u16*)(ws + OFF_W1T);

    int nchunk = 128;
    if (ws_size < ((size_t)OFF_GP + 49152ull * 128) * 4) nchunk = 64;
    if (ws_size < ((size_t)OFF_GP + 49152ull * 64) * 4)  nchunk = 32;
    const int Kc = N_PTS / nchunk;

    hipLaunchKernelGGL(kA,       dim3(2368), dim3(256), 0, stream,
                       F, W1, cats, Fb, FbT, W1T, ws);
    hipLaunchKernelGGL(kB,       dim3(3 * nchunk + 256), dim3(512), 0, stream,
                       FbT, ws, nchunk, Kc);
    hipLaunchKernelGGL(kC,       dim3(256),  dim3(256), 0, stream, cats, ws, nchunk);
    hipLaunchKernelGGL(kD,       dim3(1024), dim3(256), 0, stream, W1, W1T, ws);
    hipLaunchKernelGGL(k5_mfma,  dim3(528),  dim3(512), 0, stream,
                       Fb, W1T, Wc, gamma, beta, bias, shifts, seglens, ws, out);
}

// Round 18
// 106.168 us; speedup vs baseline: 1.1784x; 1.1784x over previous
//
#include <hip/hip_runtime.h>
#include <hip/hip_bf16.h>
#include <math.h>

#define N_PTS 32768
#define IN_F  256
#define NUM_CAT 16
#define CF    4096
#define NSEG  6
#define OUTK  50
#define BN_EPS 1e-5f

typedef unsigned short u16;
typedef __attribute__((ext_vector_type(8))) short bf16x8;
typedef __attribute__((ext_vector_type(4))) float f32x4;
typedef __attribute__((ext_vector_type(4))) unsigned int u32x4;
typedef __attribute__((ext_vector_type(8))) unsigned short u16x8;

// ---- ws layout (float offsets) ----
#define OFF_G     0u          // 256*256
#define OFF_FBAR  65536u      // 256
#define OFF_LUT   65792u      // TILECAT LUT: 528 ints
#define OFF_INT   73984u      // int region (33440 ints)
#define OFF_FB    107424u     // F bf16 [32768][256]
#define OFF_FBT   4301728u    // F^T bf16 [256][32768]
#define OFF_W1T   8496032u    // W1T bf16 [16][256 n][256 k]
#define OFF_GP    9020320u    // Gram partials [chunk][49152] (3 tiles x 128x128)
#define OFF_VP    OFF_GP              // 8 * 4096 floats (after kC)
#define OFF_MU    (OFF_GP + 32768u)   // 4096 floats
#define IO_CATOFF 16          // 17 ints
#define IO_ORDER  67          // 32768 ints
#define IO_PC     32835       // u16[64][16]

__device__ __forceinline__ void gload_lds16(const void* g, void* l) {
    __builtin_amdgcn_global_load_lds(
        (const __attribute__((address_space(1))) void*)g,
        (__attribute__((address_space(3))) void*)l,
        16, 0, 0);
}
__device__ __forceinline__ u16 f2bf(float f) {
    unsigned int u = __float_as_uint(f);
    return (u16)((u + 0x7FFF + ((u >> 16) & 1)) >> 16);
}
__device__ __forceinline__ float bf2f(u16 h) {
    return __uint_as_float((unsigned int)h << 16);
}

// ============ kA: F->Fb/FbT convert (2048) | W1->W1T (256) | hist partials (64) ====
__global__ __launch_bounds__(256) void kA(const float* __restrict__ F,
                                          const float* __restrict__ W1,
                                          const int* __restrict__ cats,
                                          u16* __restrict__ Fb,
                                          u16* __restrict__ FbT,
                                          u16* __restrict__ W1T,
                                          float* __restrict__ ws) {
    const int b = blockIdx.x;
    const int tid = threadIdx.x;
    __shared__ u16 T[64][72];
    __shared__ int h[16];

    if (b < 2048) {
        const int pb = b >> 2, fb = b & 3;
        const int p0 = pb * 64, f0 = fb * 64;
        {
            int p = tid >> 2, fq = tid & 3;
            const float* src = &F[(size_t)(p0 + p) * IN_F + f0 + fq * 16];
            u16x8 o0, o1;
            float4 v0 = *(const float4*)&src[0];
            float4 v1 = *(const float4*)&src[4];
            float4 v2 = *(const float4*)&src[8];
            float4 v3 = *(const float4*)&src[12];
            o0[0]=f2bf(v0.x); o0[1]=f2bf(v0.y); o0[2]=f2bf(v0.z); o0[3]=f2bf(v0.w);
            o0[4]=f2bf(v1.x); o0[5]=f2bf(v1.y); o0[6]=f2bf(v1.z); o0[7]=f2bf(v1.w);
            o1[0]=f2bf(v2.x); o1[1]=f2bf(v2.y); o1[2]=f2bf(v2.z); o1[3]=f2bf(v2.w);
            o1[4]=f2bf(v3.x); o1[5]=f2bf(v3.y); o1[6]=f2bf(v3.z); o1[7]=f2bf(v3.w);
            u16* dst = &Fb[(size_t)(p0 + p) * IN_F + f0 + fq * 16];
            *(u16x8*)dst = o0; *(u16x8*)&dst[8] = o1;
            *(u16x8*)&T[p][fq * 16] = o0; *(u16x8*)&T[p][fq * 16 + 8] = o1;
        }
        __syncthreads();
        {
            int f = tid >> 2, pq = tid & 3;
            u16x8 a0, a1;
#pragma unroll
            for (int m = 0; m < 8; m++) { a0[m] = T[pq*16 + m][f]; a1[m] = T[pq*16 + 8 + m][f]; }
            u16* dst = &FbT[(size_t)(f0 + f) * N_PTS + p0 + pq * 16];
            *(u16x8*)dst = a0; *(u16x8*)&dst[8] = a1;
        }
    } else if (b < 2304) {
        const int bb = b - 2048;
        const int kb = bb & 3, jb = bb >> 2;
        {
            int kk = tid >> 2, j4 = (tid & 3) * 16;
            const float* src = &W1[(size_t)(kb * 64 + kk) * CF + jb * 64 + j4];
#pragma unroll
            for (int q = 0; q < 4; q++) {
                float4 v = *(const float4*)&src[q * 4];
                T[kk][j4 + q * 4 + 0] = f2bf(v.x); T[kk][j4 + q * 4 + 1] = f2bf(v.y);
                T[kk][j4 + q * 4 + 2] = f2bf(v.z); T[kk][j4 + q * 4 + 3] = f2bf(v.w);
            }
        }
        __syncthreads();
        {
            int jj = tid >> 2, ks = (tid & 3) * 16;
            int c = jb >> 2, n = (jb & 3) * 64 + jj;
            u16* dst = &W1T[((size_t)(c * 256 + n)) * 256 + kb * 64 + ks];
            u16x8 o0, o1;
#pragma unroll
            for (int m = 0; m < 8; m++) { o0[m] = T[ks + m][jj]; o1[m] = T[ks + 8 + m][jj]; }
            *(u16x8*)dst = o0;
            *(u16x8*)&dst[8] = o1;
        }
    } else {
        const int hb = b - 2304;
        if (tid < 16) h[tid] = 0;
        __syncthreads();
        const int n0 = hb * 512;
        atomicAdd(&h[cats[n0 + tid]], 1);
        atomicAdd(&h[cats[n0 + 256 + tid]], 1);
        __syncthreads();
        if (tid < 16) {
            u16* pc = (u16*)((int*)(ws + OFF_INT) + IO_PC);
            pc[hb * 16 + tid] = (u16)h[tid];
        }
    }
}

// ============ kB: Gram 128x128 tiles (3*nchunk) | column means (256) ============
__global__ __launch_bounds__(512) void kB(const u16* __restrict__ FbT,
                                          float* __restrict__ ws,
                                          int nchunk, int Kc) {
    const int tid = threadIdx.x;
    __shared__ __align__(16) u16 SA[2][8192];
    __shared__ __align__(16) u16 SB[2][8192];
    __shared__ float ps[8];

    if ((int)blockIdx.x < 3 * nchunk) {
        const int tile = blockIdx.x % 3, chunk = blockIdx.x / 3;
        const int i0 = (tile == 2) ? 128 : 0;
        const int j0 = (tile == 0) ? 0 : 128;
        const bool diag = (tile != 1);
        const int r0 = chunk * Kc;
        const int wv = tid >> 6, ln = tid & 63, g = ln >> 4, r16 = ln & 15;

        const int f0_ = (wv * 2 + 0) * 64 + ln, f1_ = (wv * 2 + 1) * 64 + ln;
        const int row0 = f0_ >> 3, u0 = f0_ & 7, k0off = ((u0 ^ (row0 & 7)) << 3);
        const int row1 = f1_ >> 3, u1 = f1_ & 7, k1off = ((u1 ^ (row1 & 7)) << 3);

        f32x4 acc8[8];
#pragma unroll
        for (int nt = 0; nt < 8; nt++)
#pragma unroll
            for (int i = 0; i < 4; i++) acc8[nt][i] = 0.f;

        const int nslab = Kc >> 6;
#define KB_STAGE(s, bf)                                                            \
        {   int p0s = r0 + (s) * 64;                                               \
            gload_lds16(FbT + (size_t)(i0 + row0) * N_PTS + p0s + k0off,           \
                        (char*)SA[bf] + (wv * 2 + 0) * 1024);                      \
            gload_lds16(FbT + (size_t)(i0 + row1) * N_PTS + p0s + k1off,           \
                        (char*)SA[bf] + (wv * 2 + 1) * 1024);                      \
            if (!diag) {                                                           \
                gload_lds16(FbT + (size_t)(j0 + row0) * N_PTS + p0s + k0off,       \
                            (char*)SB[bf] + (wv * 2 + 0) * 1024);                  \
                gload_lds16(FbT + (size_t)(j0 + row1) * N_PTS + p0s + k1off,       \
                            (char*)SB[bf] + (wv * 2 + 1) * 1024);                  \
            }                                                                      \
        }

        KB_STAGE(0, 0);
        __syncthreads();
        for (int s = 0; s < nslab; s++) {
            const int bf = s & 1;
            if (s + 1 < nslab) KB_STAGE(s + 1, bf ^ 1);
            const char* BB = diag ? (const char*)SA[bf] : (const char*)SB[bf];
#pragma unroll
            for (int ks = 0; ks < 2; ks++) {
                const int row = wv * 16 + r16;
                const int pha = ((ks * 4 + g) ^ (row & 7)) * 16;
                bf16x8 a = *(const bf16x8*)((const char*)SA[bf] + row * 128 + pha);
#pragma unroll
                for (int nt = 0; nt < 8; nt++) {
                    const int cr = nt * 16 + r16;
                    const int phb = ((ks * 4 + g) ^ (cr & 7)) * 16;
                    bf16x8 bb = *(const bf16x8*)(BB + cr * 128 + phb);
                    acc8[nt] = __builtin_amdgcn_mfma_f32_16x16x32_bf16(a, bb, acc8[nt], 0, 0, 0);
                }
            }
            __syncthreads();
        }
        float* Gp = ws + OFF_GP + (size_t)chunk * 49152 + tile * 16384;
#pragma unroll
        for (int nt = 0; nt < 8; nt++)
#pragma unroll
            for (int i = 0; i < 4; i++)
                Gp[(wv * 16 + g * 4 + i) * 128 + nt * 16 + r16] = acc8[nt][i];
    } else {
        const int row = blockIdx.x - 3 * nchunk;
        const u16* r = FbT + (size_t)row * N_PTS;
        float s = 0.f;
        for (int i = tid * 8; i < N_PTS; i += 4096) {
            u16x8 v = *(const u16x8*)&r[i];
#pragma unroll
            for (int m = 0; m < 8; m++) s += bf2f(v[m]);
        }
#pragma unroll
        for (int off = 32; off >= 1; off >>= 1) s += __shfl_xor(s, off);
        if ((tid & 63) == 0) ps[tid >> 6] = s;
        __syncthreads();
        if (tid == 0) {
            float t = 0.f;
#pragma unroll
            for (int w = 0; w < 8; w++) t += ps[w];
            ws[OFF_FBAR + row] = t * (1.0f / N_PTS);
        }
    }
}

// ============ kC: reduce Gram partials -> G (192) | scatter + TILECAT LUT (64) ====
__global__ __launch_bounds__(256) void kC(const int* __restrict__ cats,
                                          float* __restrict__ ws, int nchunk) {
    const int tid = threadIdx.x;
    int* wi = (int*)(ws + OFF_INT);
    __shared__ int tot[16], bbs[16], coff[17], lh[16], tst[17];

    if (blockIdx.x < 192) {
        const int e = blockIdx.x * 256 + tid;
        const float* p = ws + OFF_GP + e;
        float s = 0.f;
        for (int c = 0; c < nchunk; c++) s += p[(size_t)c * 49152];
        const int t = e >> 14, x = (e >> 7) & 127, y = e & 127;
        const int a = ((t == 2) ? 128 : 0) + x;
        const int bcol = ((t == 0) ? 0 : 128) + y;
        ws[OFF_G + a * 256 + bcol] = s;
        ws[OFF_G + bcol * 256 + a] = s;
    } else {
        const int sb = blockIdx.x - 192;
        const u16* pc = (const u16*)(wi + IO_PC);
        if (tid < 16) {
            int T = 0, B = 0;
            for (int b2 = 0; b2 < 64; b2++) {
                int v = pc[b2 * 16 + tid];
                T += v;
                if (b2 < sb) B += v;
            }
            tot[tid] = T; bbs[tid] = B; lh[tid] = 0;
        }
        __syncthreads();
        if (tid == 0) {
            int co = 0, ts = 0;
            for (int c = 0; c < 16; c++) {
                coff[c] = co; tst[c] = ts;
                co += tot[c]; ts += (tot[c] + 63) >> 6;
            }
            coff[16] = co; tst[16] = ts;
        }
        __syncthreads();
        const int n0 = sb * 512;
        {
            int cA = cats[n0 + tid];
            int rA = atomicAdd(&lh[cA], 1);
            wi[IO_ORDER + coff[cA] + bbs[cA] + rA] = n0 + tid;
        }
        {
            int cB = cats[n0 + 256 + tid];
            int rB = atomicAdd(&lh[cB], 1);
            wi[IO_ORDER + coff[cB] + bbs[cB] + rB] = n0 + 256 + tid;
        }
        if (sb == 0) {
            if (tid < 17) wi[IO_CATOFF + tid] = coff[tid];
            int* lut = (int*)(ws + OFF_LUT);
            for (int t = tid; t < 528; t += 256) {
                int info = -1;
                if (t < tst[16]) {
                    int c = 0;
                    while (!(t >= tst[c] && t < tst[c + 1])) c++;
                    int lt = t - tst[c];
                    int npts = min(64, tot[c] - lt * 64);
                    int b = coff[c] + lt * 64;
                    info = c | ((npts - 1) << 4) | (b << 10);
                }
                lut[t] = info;
            }
        }
    }
}

// ============ kD: w^T G w split-b partials (128 colgrp x 8 b-splits) ============
__global__ __launch_bounds__(256) void kD(const float* __restrict__ W1,
                                          const u16* __restrict__ W1T,
                                          float* __restrict__ ws) {
    const int tid = threadIdx.x;
    const int jg = blockIdx.x >> 3, sp = blockIdx.x & 7;
    const int j0 = jg * 32;
    const int c = jg >> 3, n0 = (jg & 7) * 32;
    __shared__ float pwv[32][4], pwm[32][4];

    float acc[32];
#pragma unroll
    for (int jj = 0; jj < 32; jj++) acc[jj] = 0.f;

    const float* Gs = ws + OFF_G + (size_t)(sp * 32) * 256;
#pragma unroll 2
    for (int b = 0; b < 32; b++) {
        const float g = Gs[b * 256 + tid];
        const float* wrow = W1 + (size_t)(sp * 32 + b) * CF + j0;
#pragma unroll
        for (int jj = 0; jj < 32; jj++)
            acc[jj] += g * wrow[jj];
    }

    const int lane = tid & 63, wave = tid >> 6;
    const float fb = ws[OFF_FBAR + tid];
#pragma unroll
    for (int jj = 0; jj < 32; jj++) {
        const float wk = bf2f(W1T[((size_t)(c * 256 + n0 + jj)) * 256 + tid]);
        float v = wk * acc[jj];
#pragma unroll
        for (int off = 32; off >= 1; off >>= 1) v += __shfl_xor(v, off);
        if (lane == 0) pwv[jj][wave] = v;
        if (sp == 0) {
            float m = fb * wk;
#pragma unroll
            for (int off = 32; off >= 1; off >>= 1) m += __shfl_xor(m, off);
            if (lane == 0) pwm[jj][wave] = m;
        }
    }
    __syncthreads();
    if (tid < 32) {
        float v = pwv[tid][0] + pwv[tid][1] + pwv[tid][2] + pwv[tid][3];
        ws[OFF_VP + sp * 4096 + j0 + tid] = v;
        if (sp == 0) {
            float m = pwm[tid][0] + pwm[tid][1] + pwm[tid][2] + pwm[tid][3];
            ws[OFF_MU + j0 + tid] = m;
        }
    }
}

// ============ K5: bf16-MFMA GEMM — pinned W + MFMA epilogue + LUT dispatch ============
__global__ __launch_bounds__(512, 4) void k5_mfma(const u16* __restrict__ Fb,
                                                  const u16* __restrict__ W1T,
                                                  const float* __restrict__ Wc,
                                                  const float* __restrict__ gamma,
                                                  const float* __restrict__ beta,
                                                  const float* __restrict__ bias,
                                                  const int* __restrict__ shifts,
                                                  const int* __restrict__ seg_lens,
                                                  const float* __restrict__ ws,
                                                  float* __restrict__ out) {
    const int* wi = (const int*)(ws + OFF_INT);
    const int bid = blockIdx.x;
    const int t = (bid & 7) * 66 + (bid >> 3);   // 528 = 8 x 66, bijective
    const int info = ((const int*)(ws + OFF_LUT))[t];
    if (info < 0) return;
    const int c    = info & 15;
    const int npts = ((info >> 4) & 63) + 1;
    const int base = ((unsigned)info) >> 10;
    const int tid = threadIdx.x;
    const int wv = tid >> 6, ln = tid & 63;
    const int g = ln >> 4, r16 = ln & 15, r7 = r16 & 7;

    __shared__ __align__(16) u16 Fl[16384];     // 32 KB: F tile, then X
    __shared__ float red[64][8][8];             // 16 KB
    __shared__ int plds[64];

    if (tid < 64) plds[tid] = wi[IO_ORDER + base + min(tid, npts - 1)];
    const int col0 = wv * 32 + r16, col1 = col0 + 16;
    const float biasj = ((tid & 7) < 6) ? bias[tid & 7] : 0.f;
    const int shc = shifts[c], lnc = seg_lens[c];

    // Wc B-fragment: lane holds B[k = wv*32 + g*8 + j][n = r16], n>=6 -> 0
    bf16x8 bwc;
#pragma unroll
    for (int j = 0; j < 8; j++) {
        float v = (r16 < 6) ? Wc[(size_t)c * 1536 + (wv * 32 + g * 8 + j) * 6 + r16] : 0.f;
        bwc[j] = (short)f2bf(v);
    }
    __syncthreads();                            // plds visible

    // ---- issue F staging (gathered, swizzled source) ----
#pragma unroll
    for (int s = 0; s < 4; s++) {
        int flat = (wv * 4 + s) * 64 + ln;
        int pt = flat >> 5, u = flat & 31;
        const u16* src = Fb + (size_t)plds[pt] * 256 + ((u ^ (pt & 7)) << 3);
        gload_lds16(src, (char*)Fl + (size_t)(wv * 4 + s) * 1024);
    }

    // ---- asm-pinned W loads: 16 x 16B into 64 VGPRs ----
    const u16* W1Tc = W1T + (size_t)c * 65536;
    unsigned long long a0 = (unsigned long long)(W1Tc + (size_t)col0 * 256 + g * 8);
    unsigned long long a1 = (unsigned long long)(W1Tc + (size_t)col1 * 256 + g * 8);
    u32x4 wr[16];
#pragma unroll
    for (int kc = 0; kc < 8; kc++) {
        asm volatile("global_load_dwordx4 %0, %1, off offset:%2"
                     : "=v"(wr[kc * 2])     : "v"(a0), "i"(kc * 64));
        asm volatile("global_load_dwordx4 %0, %1, off offset:%2"
                     : "=v"(wr[kc * 2 + 1]) : "v"(a1), "i"(kc * 64));
    }

    __syncthreads();    // implicit s_waitcnt vmcnt(0): F staged AND all wr ready

    f32x4 acc[4][2];
#pragma unroll
    for (int mt = 0; mt < 4; mt++)
#pragma unroll
        for (int nt = 0; nt < 2; nt++)
#pragma unroll
            for (int i = 0; i < 4; i++) acc[mt][nt][i] = 0.f;

#pragma unroll
    for (int kc = 0; kc < 8; kc++) {
        bf16x8 b0 = __builtin_bit_cast(bf16x8, wr[kc * 2]);
        bf16x8 b1 = __builtin_bit_cast(bf16x8, wr[kc * 2 + 1]);
#pragma unroll
        for (int mt = 0; mt < 4; mt++) {
            int row = mt * 16 + r16;
            int ph = ((kc * 4 + g) ^ r7) * 16;
            bf16x8 af = *(const bf16x8*)((const char*)Fl + (size_t)row * 512 + ph);
            acc[mt][0] = __builtin_amdgcn_mfma_f32_16x16x32_bf16(af, b0, acc[mt][0], 0, 0, 0);
            acc[mt][1] = __builtin_amdgcn_mfma_f32_16x16x32_bf16(af, b1, acc[mt][1], 0, 0, 0);
        }
    }

    // ---- BN constants inline from VP/MU ----
    float vv0 = 0.f, vv1 = 0.f;
#pragma unroll
    for (int sp = 0; sp < 8; sp++) {
        vv0 += ws[OFF_VP + sp * 4096 + c * 256 + col0];
        vv1 += ws[OFF_VP + sp * 4096 + c * 256 + col1];
    }
    const float mu0 = ws[OFF_MU + c * 256 + col0];
    const float mu1 = ws[OFF_MU + c * 256 + col1];
    const float sc0 = gamma[c * 256 + col0] * rsqrtf(vv0 * (1.0f / N_PTS) - mu0 * mu0 + BN_EPS);
    const float sc1 = gamma[c * 256 + col1] * rsqrtf(vv1 * (1.0f / N_PTS) - mu1 * mu1 + BN_EPS);
    const float sh0 = beta[c * 256 + col0] - mu0 * sc0;
    const float sh1 = beta[c * 256 + col1] - mu1 * sc1;

    __syncthreads();    // all Fl reads done; safe to overwrite with X

    // ---- BN + LeakyReLU -> X bf16 into Fl (swizzled 16B units by row&7) ----
#pragma unroll
    for (int mt = 0; mt < 4; mt++)
#pragma unroll
        for (int i = 0; i < 4; i++) {
            const int row = mt * 16 + g * 4 + i;
            float x0 = acc[mt][0][i] * sc0 + sh0;  x0 = (x0 >= 0.f) ? x0 : 0.2f * x0;
            float x1 = acc[mt][1][i] * sc1 + sh1;  x1 = (x1 >= 0.f) ? x1 : 0.2f * x1;
            {
                const int u = (col0 >> 3) ^ (row & 7);
                *(u16*)((char*)Fl + row * 512 + u * 16 + (col0 & 7) * 2) = f2bf(x0);
            }
            {
                const int u = (col1 >> 3) ^ (row & 7);
                *(u16*)((char*)Fl + row * 512 + u * 16 + (col1 & 7) * 2) = f2bf(x1);
            }
        }
    __syncthreads();

    // ---- logits partials via MFMA: X (wave K-slice) x Wc ----
    f32x4 zero = {0.f, 0.f, 0.f, 0.f};
#pragma unroll
    for (int mt = 0; mt < 4; mt++) {
        const int ar = mt * 16 + r16;
        const int au = (wv * 4 + g) ^ (ar & 7);
        bf16x8 ax = *(const bf16x8*)((const char*)Fl + ar * 512 + au * 16);
        f32x4 pc = __builtin_amdgcn_mfma_f32_16x16x32_bf16(ax, bwc, zero, 0, 0, 0);
        if (r16 < 8) {
#pragma unroll
            for (int i = 0; i < 4; i++)
                red[mt * 16 + g * 4 + i][wv][r16] = pc[i];
        }
    }
    __syncthreads();

    // ---- finalize: 64 pts x 8 lanes ----
    {
        const int lpt = tid >> 3, j = tid & 7;
        float v = -1e30f;
        if (j < 6) {
            v = biasj;
#pragma unroll
            for (int w = 0; w < 8; w++) v += red[lpt][w][j];
        }
        float mx = v;
        mx = fmaxf(mx, __shfl_xor(mx, 1));
        mx = fmaxf(mx, __shfl_xor(mx, 2));
        mx = fmaxf(mx, __shfl_xor(mx, 4));
        float e = (j < 6) ? expf(v - mx) : 0.f;
        float se = e;
        se += __shfl_xor(se, 1);
        se += __shfl_xor(se, 2);
        se += __shfl_xor(se, 4);
        float lsm = v - (mx + logf(se));
        if (lpt < npts) {
            const int pid = plds[lpt];
            float* orow = out + (size_t)pid * OUTK;
            const int gb = ln & 56;
#pragma unroll
            for (int it = 0; it < 7; it++) {
                int k = j + it * 8;
                int jj = k - shc;
                int jc = min(max(jj, 0), 5);
                float val = __shfl(lsm, gb | jc);
                if (k < OUTK)
                    orow[k] = (jj >= 0 && jj < lnc) ? val : 0.f;
            }
        }
    }
}

extern "C" void kernel_launch(void* const* d_in, const int* in_sizes, int n_in,
                              void* d_out, int out_size, void* d_ws, size_t ws_size,
                              hipStream_t stream) {
    const float* F      = (const float*)d_in[0];
    const float* W1     = (const float*)d_in[1];
    const float* gamma  = (const float*)d_in[2];
    const float* beta   = (const float*)d_in[3];
    const float* Wc     = (const float*)d_in[4];
    const float* bias   = (const float*)d_in[5];
    const int*  cats    = (const int*)d_in[6];
    const int*  shifts  = (const int*)d_in[7];
    const int*  seglens = (const int*)d_in[8];
    float* out = (float*)d_out;
    float* ws  = (float*)d_ws;
    u16* Fb  = (u16*)(ws + OFF_FB);
    u16* FbT = (u16*)(ws + OFF_FBT);
    u16* W1T = (u16*)(ws + OFF_W1T);

    int nchunk = 64;
    if (ws_size < ((size_t)OFF_GP + 49152ull * 64) * 4) nchunk = 32;
    const int Kc = N_PTS / nchunk;

    hipLaunchKernelGGL(kA,       dim3(2368), dim3(256), 0, stream,
                       F, W1, cats, Fb, FbT, W1T, ws);
    hipLaunchKernelGGL(kB,       dim3(3 * nchunk + 256), dim3(512), 0, stream,
                       FbT, ws, nchunk, Kc);
    hipLaunchKernelGGL(kC,       dim3(256),  dim3(256), 0, stream, cats, ws, nchunk);
    hipLaunchKernelGGL(kD,       dim3(1024), dim3(256), 0, stream, W1, W1T, ws);
    hipLaunchKernelGGL(k5_mfma,  dim3(528),  dim3(512), 0, stream,
                       Fb, W1T, Wc, gamma, beta, bias, shifts, seglens, ws, out);
}

// Round 21
// 106.042 us; speedup vs baseline: 1.1798x; 1.0012x over previous
//
#include <hip/hip_runtime.h>
#include <hip/hip_bf16.h>
#include <math.h>

#define N_PTS 32768
#define IN_F  256
#define NUM_CAT 16
#define CF    4096
#define NSEG  6
#define OUTK  50
#define BN_EPS 1e-5f

typedef unsigned short u16;
typedef __attribute__((ext_vector_type(8))) short bf16x8;
typedef __attribute__((ext_vector_type(4))) float f32x4;
typedef __attribute__((ext_vector_type(4))) unsigned int u32x4;
typedef __attribute__((ext_vector_type(8))) unsigned short u16x8;

// ---- ws layout (float offsets) ----
#define OFF_G     0u          // 256*256
#define OFF_FBAR  65536u      // 256
#define OFF_LUT   65792u      // TILECAT LUT: 528 ints
#define OFF_INT   73984u      // int region (33440 ints)
#define OFF_FB    107424u     // F bf16 [32768][256]
#define OFF_FBT   4301728u    // F^T bf16 [256][32768]
#define OFF_W1T   8496032u    // W1T bf16 [16][256 n][256 k]
#define OFF_GP    9020320u    // Gram partials [chunk][49152] (3 tiles x 128x128)
#define OFF_VP    OFF_GP              // 8 * 4096 floats (after kC)
#define OFF_MU    (OFF_GP + 32768u)   // 4096 floats
#define IO_CATOFF 16          // 17 ints
#define IO_ORDER  67          // 32768 ints
#define IO_PC     32835       // u16[64][16]

__device__ __forceinline__ void gload_lds16(const void* g, void* l) {
    __builtin_amdgcn_global_load_lds(
        (const __attribute__((address_space(1))) void*)g,
        (__attribute__((address_space(3))) void*)l,
        16, 0, 0);
}
__device__ __forceinline__ u16 f2bf(float f) {
    unsigned int u = __float_as_uint(f);
    return (u16)((u + 0x7FFF + ((u >> 16) & 1)) >> 16);
}
__device__ __forceinline__ float bf2f(u16 h) {
    return __uint_as_float((unsigned int)h << 16);
}

// ============ kA: F->Fb/FbT convert (2048) | W1->W1T (256) | hist partials (64) ====
__global__ __launch_bounds__(256) void kA(const float* __restrict__ F,
                                          const float* __restrict__ W1,
                                          const int* __restrict__ cats,
                                          u16* __restrict__ Fb,
                                          u16* __restrict__ FbT,
                                          u16* __restrict__ W1T,
                                          float* __restrict__ ws) {
    const int b = blockIdx.x;
    const int tid = threadIdx.x;
    __shared__ u16 T[64][72];
    __shared__ int h[16];

    if (b < 2048) {
        const int pb = b >> 2, fb = b & 3;
        const int p0 = pb * 64, f0 = fb * 64;
        {
            int p = tid >> 2, fq = tid & 3;
            const float* src = &F[(size_t)(p0 + p) * IN_F + f0 + fq * 16];
            u16x8 o0, o1;
            float4 v0 = *(const float4*)&src[0];
            float4 v1 = *(const float4*)&src[4];
            float4 v2 = *(const float4*)&src[8];
            float4 v3 = *(const float4*)&src[12];
            o0[0]=f2bf(v0.x); o0[1]=f2bf(v0.y); o0[2]=f2bf(v0.z); o0[3]=f2bf(v0.w);
            o0[4]=f2bf(v1.x); o0[5]=f2bf(v1.y); o0[6]=f2bf(v1.z); o0[7]=f2bf(v1.w);
            o1[0]=f2bf(v2.x); o1[1]=f2bf(v2.y); o1[2]=f2bf(v2.z); o1[3]=f2bf(v2.w);
            o1[4]=f2bf(v3.x); o1[5]=f2bf(v3.y); o1[6]=f2bf(v3.z); o1[7]=f2bf(v3.w);
            u16* dst = &Fb[(size_t)(p0 + p) * IN_F + f0 + fq * 16];
            *(u16x8*)dst = o0; *(u16x8*)&dst[8] = o1;
            *(u16x8*)&T[p][fq * 16] = o0; *(u16x8*)&T[p][fq * 16 + 8] = o1;
        }
        __syncthreads();
        {
            int f = tid >> 2, pq = tid & 3;
            u16x8 a0, a1;
#pragma unroll
            for (int m = 0; m < 8; m++) { a0[m] = T[pq*16 + m][f]; a1[m] = T[pq*16 + 8 + m][f]; }
            u16* dst = &FbT[(size_t)(f0 + f) * N_PTS + p0 + pq * 16];
            *(u16x8*)dst = a0; *(u16x8*)&dst[8] = a1;
        }
    } else if (b < 2304) {
        const int bb = b - 2048;
        const int kb = bb & 3, jb = bb >> 2;
        {
            int kk = tid >> 2, j4 = (tid & 3) * 16;
            const float* src = &W1[(size_t)(kb * 64 + kk) * CF + jb * 64 + j4];
#pragma unroll
            for (int q = 0; q < 4; q++) {
                float4 v = *(const float4*)&src[q * 4];
                T[kk][j4 + q * 4 + 0] = f2bf(v.x); T[kk][j4 + q * 4 + 1] = f2bf(v.y);
                T[kk][j4 + q * 4 + 2] = f2bf(v.z); T[kk][j4 + q * 4 + 3] = f2bf(v.w);
            }
        }
        __syncthreads();
        {
            int jj = tid >> 2, ks = (tid & 3) * 16;
            int c = jb >> 2, n = (jb & 3) * 64 + jj;
            u16* dst = &W1T[((size_t)(c * 256 + n)) * 256 + kb * 64 + ks];
            u16x8 o0, o1;
#pragma unroll
            for (int m = 0; m < 8; m++) { o0[m] = T[ks + m][jj]; o1[m] = T[ks + 8 + m][jj]; }
            *(u16x8*)dst = o0;
            *(u16x8*)&dst[8] = o1;
        }
    } else {
        const int hb = b - 2304;
        if (tid < 16) h[tid] = 0;
        __syncthreads();
        const int n0 = hb * 512;
        atomicAdd(&h[cats[n0 + tid]], 1);
        atomicAdd(&h[cats[n0 + 256 + tid]], 1);
        __syncthreads();
        if (tid < 16) {
            u16* pc = (u16*)((int*)(ws + OFF_INT) + IO_PC);
            pc[hb * 16 + tid] = (u16)h[tid];
        }
    }
}

// ============ kB: Gram 128x128 tiles (3*nchunk) | column means (256) ============
__global__ __launch_bounds__(512) void kB(const u16* __restrict__ FbT,
                                          float* __restrict__ ws,
                                          int nchunk, int Kc) {
    const int tid = threadIdx.x;
    __shared__ __align__(16) u16 SA[2][8192];
    __shared__ __align__(16) u16 SB[2][8192];
    __shared__ float ps[8];

    if ((int)blockIdx.x < 3 * nchunk) {
        const int tile = blockIdx.x % 3, chunk = blockIdx.x / 3;
        const int i0 = (tile == 2) ? 128 : 0;
        const int j0 = (tile == 0) ? 0 : 128;
        const bool diag = (tile != 1);
        const int r0 = chunk * Kc;
        const int wv = tid >> 6, ln = tid & 63, g = ln >> 4, r16 = ln & 15;

        const int f0_ = (wv * 2 + 0) * 64 + ln, f1_ = (wv * 2 + 1) * 64 + ln;
        const int row0 = f0_ >> 3, u0 = f0_ & 7, k0off = ((u0 ^ (row0 & 7)) << 3);
        const int row1 = f1_ >> 3, u1 = f1_ & 7, k1off = ((u1 ^ (row1 & 7)) << 3);

        f32x4 acc8[8];
#pragma unroll
        for (int nt = 0; nt < 8; nt++)
#pragma unroll
            for (int i = 0; i < 4; i++) acc8[nt][i] = 0.f;

        const int nslab = Kc >> 6;
#define KB_STAGE(s, bf)                                                            \
        {   int p0s = r0 + (s) * 64;                                               \
            gload_lds16(FbT + (size_t)(i0 + row0) * N_PTS + p0s + k0off,           \
                        (char*)SA[bf] + (wv * 2 + 0) * 1024);                      \
            gload_lds16(FbT + (size_t)(i0 + row1) * N_PTS + p0s + k1off,           \
                        (char*)SA[bf] + (wv * 2 + 1) * 1024);                      \
            if (!diag) {                                                           \
                gload_lds16(FbT + (size_t)(j0 + row0) * N_PTS + p0s + k0off,       \
                            (char*)SB[bf] + (wv * 2 + 0) * 1024);                  \
                gload_lds16(FbT + (size_t)(j0 + row1) * N_PTS + p0s + k1off,       \
                            (char*)SB[bf] + (wv * 2 + 1) * 1024);                  \
            }                                                                      \
        }

        KB_STAGE(0, 0);
        __syncthreads();
        for (int s = 0; s < nslab; s++) {
            const int bf = s & 1;
            if (s + 1 < nslab) KB_STAGE(s + 1, bf ^ 1);
            const char* BB = diag ? (const char*)SA[bf] : (const char*)SB[bf];
#pragma unroll
            for (int ks = 0; ks < 2; ks++) {
                const int row = wv * 16 + r16;
                const int pha = ((ks * 4 + g) ^ (row & 7)) * 16;
                bf16x8 a = *(const bf16x8*)((const char*)SA[bf] + row * 128 + pha);
#pragma unroll
                for (int nt = 0; nt < 8; nt++) {
                    const int cr = nt * 16 + r16;
                    const int phb = ((ks * 4 + g) ^ (cr & 7)) * 16;
                    bf16x8 bb = *(const bf16x8*)(BB + cr * 128 + phb);
                    acc8[nt] = __builtin_amdgcn_mfma_f32_16x16x32_bf16(a, bb, acc8[nt], 0, 0, 0);
                }
            }
            __syncthreads();
        }
        float* Gp = ws + OFF_GP + (size_t)chunk * 49152 + tile * 16384;
#pragma unroll
        for (int nt = 0; nt < 8; nt++)
#pragma unroll
            for (int i = 0; i < 4; i++)
                Gp[(wv * 16 + g * 4 + i) * 128 + nt * 16 + r16] = acc8[nt][i];
    } else {
        const int row = blockIdx.x - 3 * nchunk;
        const u16* r = FbT + (size_t)row * N_PTS;
        float s = 0.f;
        for (int i = tid * 8; i < N_PTS; i += 4096) {
            u16x8 v = *(const u16x8*)&r[i];
#pragma unroll
            for (int m = 0; m < 8; m++) s += bf2f(v[m]);
        }
#pragma unroll
        for (int off = 32; off >= 1; off >>= 1) s += __shfl_xor(s, off);
        if ((tid & 63) == 0) ps[tid >> 6] = s;
        __syncthreads();
        if (tid == 0) {
            float t = 0.f;
#pragma unroll
            for (int w = 0; w < 8; w++) t += ps[w];
            ws[OFF_FBAR + row] = t * (1.0f / N_PTS);
        }
    }
}

// ============ kC: reduce Gram partials -> G (192) | scatter + TILECAT LUT (64) ====
__global__ __launch_bounds__(256) void kC(const int* __restrict__ cats,
                                          float* __restrict__ ws, int nchunk) {
    const int tid = threadIdx.x;
    int* wi = (int*)(ws + OFF_INT);
    __shared__ int tot[16], bbs[16], coff[17], lh[16], tst[17];

    if (blockIdx.x < 192) {
        const int e = blockIdx.x * 256 + tid;
        const float* p = ws + OFF_GP + e;
        float s = 0.f;
        for (int c = 0; c < nchunk; c++) s += p[(size_t)c * 49152];
        const int t = e >> 14, x = (e >> 7) & 127, y = e & 127;
        const int a = ((t == 2) ? 128 : 0) + x;
        const int bcol = ((t == 0) ? 0 : 128) + y;
        ws[OFF_G + a * 256 + bcol] = s;
        ws[OFF_G + bcol * 256 + a] = s;
    } else {
        const int sb = blockIdx.x - 192;
        const u16* pc = (const u16*)(wi + IO_PC);
        if (tid < 16) {
            int T = 0, B = 0;
            for (int b2 = 0; b2 < 64; b2++) {
                int v = pc[b2 * 16 + tid];
                T += v;
                if (b2 < sb) B += v;
            }
            tot[tid] = T; bbs[tid] = B; lh[tid] = 0;
        }
        __syncthreads();
        if (tid == 0) {
            int co = 0, ts = 0;
            for (int c = 0; c < 16; c++) {
                coff[c] = co; tst[c] = ts;
                co += tot[c]; ts += (tot[c] + 63) >> 6;
            }
            coff[16] = co; tst[16] = ts;
        }
        __syncthreads();
        const int n0 = sb * 512;
        {
            int cA = cats[n0 + tid];
            int rA = atomicAdd(&lh[cA], 1);
            wi[IO_ORDER + coff[cA] + bbs[cA] + rA] = n0 + tid;
        }
        {
            int cB = cats[n0 + 256 + tid];
            int rB = atomicAdd(&lh[cB], 1);
            wi[IO_ORDER + coff[cB] + bbs[cB] + rB] = n0 + 256 + tid;
        }
        if (sb == 0) {
            if (tid < 17) wi[IO_CATOFF + tid] = coff[tid];
            int* lut = (int*)(ws + OFF_LUT);
            for (int t = tid; t < 528; t += 256) {
                int info = -1;
                if (t < tst[16]) {
                    int c = 0;
                    while (!(t >= tst[c] && t < tst[c + 1])) c++;
                    int lt = t - tst[c];
                    int npts = min(64, tot[c] - lt * 64);
                    int b = coff[c] + lt * 64;
                    info = c | ((npts - 1) << 4) | (b << 10);
                }
                lut[t] = info;
            }
        }
    }
}

// ============ kD: w^T G w split-b partials (128 colgrp x 8 b-splits) ============
__global__ __launch_bounds__(256) void kD(const float* __restrict__ W1,
                                          const u16* __restrict__ W1T,
                                          float* __restrict__ ws) {
    const int tid = threadIdx.x;
    const int jg = blockIdx.x >> 3, sp = blockIdx.x & 7;
    const int j0 = jg * 32;
    const int c = jg >> 3, n0 = (jg & 7) * 32;
    __shared__ float pwv[32][4], pwm[32][4];

    float acc[32];
#pragma unroll
    for (int jj = 0; jj < 32; jj++) acc[jj] = 0.f;

    const float* Gs = ws + OFF_G + (size_t)(sp * 32) * 256;
#pragma unroll 2
    for (int b = 0; b < 32; b++) {
        const float g = Gs[b * 256 + tid];
        const float* wrow = W1 + (size_t)(sp * 32 + b) * CF + j0;
#pragma unroll
        for (int jj = 0; jj < 32; jj++)
            acc[jj] += g * wrow[jj];
    }

    const int lane = tid & 63, wave = tid >> 6;
    const float fb = ws[OFF_FBAR + tid];
#pragma unroll
    for (int jj = 0; jj < 32; jj++) {
        const float wk = bf2f(W1T[((size_t)(c * 256 + n0 + jj)) * 256 + tid]);
        float v = wk * acc[jj];
#pragma unroll
        for (int off = 32; off >= 1; off >>= 1) v += __shfl_xor(v, off);
        if (lane == 0) pwv[jj][wave] = v;
        if (sp == 0) {
            float m = fb * wk;
#pragma unroll
            for (int off = 32; off >= 1; off >>= 1) m += __shfl_xor(m, off);
            if (lane == 0) pwm[jj][wave] = m;
        }
    }
    __syncthreads();
    if (tid < 32) {
        float v = pwv[tid][0] + pwv[tid][1] + pwv[tid][2] + pwv[tid][3];
        ws[OFF_VP + sp * 4096 + j0 + tid] = v;
        if (sp == 0) {
            float m = pwm[tid][0] + pwm[tid][1] + pwm[tid][2] + pwm[tid][3];
            ws[OFF_MU + j0 + tid] = m;
        }
    }
}

// ============ K5: bf16-MFMA GEMM — pinned W + MFMA epilogue + LUT dispatch ============
__global__ __launch_bounds__(512, 4) void k5_mfma(const u16* __restrict__ Fb,
                                                  const u16* __restrict__ W1T,
                                                  const float* __restrict__ Wc,
                                                  const float* __restrict__ gamma,
                                                  const float* __restrict__ beta,
                                                  const float* __restrict__ bias,
                                                  const int* __restrict__ shifts,
                                                  const int* __restrict__ seg_lens,
                                                  const float* __restrict__ ws,
                                                  float* __restrict__ out) {
    const int* wi = (const int*)(ws + OFF_INT);
    const int bid = blockIdx.x;
    const int t = (bid & 7) * 66 + (bid >> 3);   // 528 = 8 x 66, bijective
    const int info = ((const int*)(ws + OFF_LUT))[t];
    if (info < 0) return;
    const int c    = info & 15;
    const int npts = ((info >> 4) & 63) + 1;
    const int base = ((unsigned)info) >> 10;
    const int tid = threadIdx.x;
    const int wv = tid >> 6, ln = tid & 63;
    const int g = ln >> 4, r16 = ln & 15, r7 = r16 & 7;

    __shared__ __align__(16) u16 Fl[16384];     // 32 KB: F tile, then X
    __shared__ float red[64][8][8];             // 16 KB
    __shared__ int plds[64];

    if (tid < 64) plds[tid] = wi[IO_ORDER + base + min(tid, npts - 1)];
    const int col0 = wv * 32 + r16, col1 = col0 + 16;
    const float biasj = ((tid & 7) < 6) ? bias[tid & 7] : 0.f;
    const int shc = shifts[c], lnc = seg_lens[c];

    // Wc B-fragment: lane holds B[k = wv*32 + g*8 + j][n = r16], n>=6 -> 0
    bf16x8 bwc;
#pragma unroll
    for (int j = 0; j < 8; j++) {
        float v = (r16 < 6) ? Wc[(size_t)c * 1536 + (wv * 32 + g * 8 + j) * 6 + r16] : 0.f;
        bwc[j] = (short)f2bf(v);
    }
    __syncthreads();                            // plds visible

    // ---- issue F staging (gathered, swizzled source) ----
#pragma unroll
    for (int s = 0; s < 4; s++) {
        int flat = (wv * 4 + s) * 64 + ln;
        int pt = flat >> 5, u = flat & 31;
        const u16* src = Fb + (size_t)plds[pt] * 256 + ((u ^ (pt & 7)) << 3);
        gload_lds16(src, (char*)Fl + (size_t)(wv * 4 + s) * 1024);
    }

    // ---- asm-pinned W loads: 16 x 16B into 64 VGPRs ----
    const u16* W1Tc = W1T + (size_t)c * 65536;
    unsigned long long a0 = (unsigned long long)(W1Tc + (size_t)col0 * 256 + g * 8);
    unsigned long long a1 = (unsigned long long)(W1Tc + (size_t)col1 * 256 + g * 8);
    u32x4 wr[16];
#pragma unroll
    for (int kc = 0; kc < 8; kc++) {
        asm volatile("global_load_dwordx4 %0, %1, off offset:%2"
                     : "=v"(wr[kc * 2])     : "v"(a0), "i"(kc * 64));
        asm volatile("global_load_dwordx4 %0, %1, off offset:%2"
                     : "=v"(wr[kc * 2 + 1]) : "v"(a1), "i"(kc * 64));
    }

    __syncthreads();    // implicit s_waitcnt vmcnt(0): F staged AND all wr ready

    f32x4 acc[4][2];
#pragma unroll
    for (int mt = 0; mt < 4; mt++)
#pragma unroll
        for (int nt = 0; nt < 2; nt++)
#pragma unroll
            for (int i = 0; i < 4; i++) acc[mt][nt][i] = 0.f;

#pragma unroll
    for (int kc = 0; kc < 8; kc++) {
        bf16x8 b0 = __builtin_bit_cast(bf16x8, wr[kc * 2]);
        bf16x8 b1 = __builtin_bit_cast(bf16x8, wr[kc * 2 + 1]);
#pragma unroll
        for (int mt = 0; mt < 4; mt++) {
            int row = mt * 16 + r16;
            int ph = ((kc * 4 + g) ^ r7) * 16;
            bf16x8 af = *(const bf16x8*)((const char*)Fl + (size_t)row * 512 + ph);
            acc[mt][0] = __builtin_amdgcn_mfma_f32_16x16x32_bf16(af, b0, acc[mt][0], 0, 0, 0);
            acc[mt][1] = __builtin_amdgcn_mfma_f32_16x16x32_bf16(af, b1, acc[mt][1], 0, 0, 0);
        }
    }

    // ---- BN constants inline from VP/MU ----
    float vv0 = 0.f, vv1 = 0.f;
#pragma unroll
    for (int sp = 0; sp < 8; sp++) {
        vv0 += ws[OFF_VP + sp * 4096 + c * 256 + col0];
        vv1 += ws[OFF_VP + sp * 4096 + c * 256 + col1];
    }
    const float mu0 = ws[OFF_MU + c * 256 + col0];
    const float mu1 = ws[OFF_MU + c * 256 + col1];
    const float sc0 = gamma[c * 256 + col0] * rsqrtf(vv0 * (1.0f / N_PTS) - mu0 * mu0 + BN_EPS);
    const float sc1 = gamma[c * 256 + col1] * rsqrtf(vv1 * (1.0f / N_PTS) - mu1 * mu1 + BN_EPS);
    const float sh0 = beta[c * 256 + col0] - mu0 * sc0;
    const float sh1 = beta[c * 256 + col1] - mu1 * sc1;

    __syncthreads();    // all Fl reads done; safe to overwrite with X

    // ---- BN + LeakyReLU -> X bf16 into Fl (swizzled 16B units by row&7) ----
#pragma unroll
    for (int mt = 0; mt < 4; mt++)
#pragma unroll
        for (int i = 0; i < 4; i++) {
            const int row = mt * 16 + g * 4 + i;
            float x0 = acc[mt][0][i] * sc0 + sh0;  x0 = (x0 >= 0.f) ? x0 : 0.2f * x0;
            float x1 = acc[mt][1][i] * sc1 + sh1;  x1 = (x1 >= 0.f) ? x1 : 0.2f * x1;
            {
                const int u = (col0 >> 3) ^ (row & 7);
                *(u16*)((char*)Fl + row * 512 + u * 16 + (col0 & 7) * 2) = f2bf(x0);
            }
            {
                const int u = (col1 >> 3) ^ (row & 7);
                *(u16*)((char*)Fl + row * 512 + u * 16 + (col1 & 7) * 2) = f2bf(x1);
            }
        }
    __syncthreads();

    // ---- logits partials via MFMA: X (wave K-slice) x Wc ----
    f32x4 zero = {0.f, 0.f, 0.f, 0.f};
#pragma unroll
    for (int mt = 0; mt < 4; mt++) {
        const int ar = mt * 16 + r16;
        const int au = (wv * 4 + g) ^ (ar & 7);
        bf16x8 ax = *(const bf16x8*)((const char*)Fl + ar * 512 + au * 16);
        f32x4 pc = __builtin_amdgcn_mfma_f32_16x16x32_bf16(ax, bwc, zero, 0, 0, 0);
        if (r16 < 8) {
#pragma unroll
            for (int i = 0; i < 4; i++)
                red[mt * 16 + g * 4 + i][wv][r16] = pc[i];
        }
    }
    __syncthreads();

    // ---- finalize: 64 pts x 8 lanes ----
    {
        const int lpt = tid >> 3, j = tid & 7;
        float v = -1e30f;
        if (j < 6) {
            v = biasj;
#pragma unroll
            for (int w = 0; w < 8; w++) v += red[lpt][w][j];
        }
        float mx = v;
        mx = fmaxf(mx, __shfl_xor(mx, 1));
        mx = fmaxf(mx, __shfl_xor(mx, 2));
        mx = fmaxf(mx, __shfl_xor(mx, 4));
        float e = (j < 6) ? expf(v - mx) : 0.f;
        float se = e;
        se += __shfl_xor(se, 1);
        se += __shfl_xor(se, 2);
        se += __shfl_xor(se, 4);
        float lsm = v - (mx + logf(se));
        if (lpt < npts) {
            const int pid = plds[lpt];
            float* orow = out + (size_t)pid * OUTK;
            const int gb = ln & 56;
#pragma unroll
            for (int it = 0; it < 7; it++) {
                int k = j + it * 8;
                int jj = k - shc;
                int jc = min(max(jj, 0), 5);
                float val = __shfl(lsm, gb | jc);
                if (k < OUTK)
                    orow[k] = (jj >= 0 && jj < lnc) ? val : 0.f;
            }
        }
    }
}

extern "C" void kernel_launch(void* const* d_in, const int* in_sizes, int n_in,
                              void* d_out, int out_size, void* d_ws, size_t ws_size,
                              hipStream_t stream) {
    const float* F      = (const float*)d_in[0];
    const float* W1     = (const float*)d_in[1];
    const float* gamma  = (const float*)d_in[2];
    const float* beta   = (const float*)d_in[3];
    const float* Wc     = (const float*)d_in[4];
    const float* bias   = (const float*)d_in[5];
    const int*  cats    = (const int*)d_in[6];
    const int*  shifts  = (const int*)d_in[7];
    const int*  seglens = (const int*)d_in[8];
    float* out = (float*)d_out;
    float* ws  = (float*)d_ws;
    u16* Fb  = (u16*)(ws + OFF_FB);
    u16* FbT = (u16*)(ws + OFF_FBT);
    u16* W1T = (u16*)(ws + OFF_W1T);

    int nchunk = 64;
    if (ws_size < ((size_t)OFF_GP + 49152ull * 64) * 4) nchunk = 32;
    const int Kc = N_PTS / nchunk;

    hipLaunchKernelGGL(kA,       dim3(2368), dim3(256), 0, stream,
                       F, W1, cats, Fb, FbT, W1T, ws);
    hipLaunchKernelGGL(kB,       dim3(3 * nchunk + 256), dim3(512), 0, stream,
                       FbT, ws, nchunk, Kc);
    hipLaunchKernelGGL(kC,       dim3(256),  dim3(256), 0, stream, cats, ws, nchunk);
    hipLaunchKernelGGL(kD,       dim3(1024), dim3(256), 0, stream, W1, W1T, ws);
    hipLaunchKernelGGL(k5_mfma,  dim3(528),  dim3(512), 0, stream,
                       Fb, W1T, Wc, gamma, beta, bias, shifts, seglens, ws, out);
}